// Round 1
// baseline (580.634 us; speedup 1.0000x reference)
//
#include <hip/hip_runtime.h>
#include <cstdint>
#include <cstddef>

typedef __bf16 bf16;
typedef __bf16 v8bf __attribute__((ext_vector_type(8)));
typedef float  v4f  __attribute__((ext_vector_type(4)));

#define D_MODEL 1024
#define FF_DIM  4096
#define SEQ     2048
#define NTOK    4096   // B*S
#define NH      16
#define HDIM    64

// ---------------- fp32 -> bf16 convert ----------------
__global__ void f32_to_bf16_kernel(const float* __restrict__ in, bf16* __restrict__ out, int n) {
    int i = (blockIdx.x * 256 + threadIdx.x) * 4;
    if (i + 3 < n) {
        float4 v = *(const float4*)(in + i);
        out[i + 0] = (bf16)v.x;
        out[i + 1] = (bf16)v.y;
        out[i + 2] = (bf16)v.z;
        out[i + 3] = (bf16)v.w;
    }
}

// ---------------- LayerNorm (unbiased std, eps on std) ----------------
__global__ __launch_bounds__(256) void layernorm_kernel(
    const float* __restrict__ x, const float* __restrict__ scale,
    const float* __restrict__ shift, bf16* __restrict__ out) {
    int row = blockIdx.x;
    int t = threadIdx.x;
    const float* xr = x + (size_t)row * D_MODEL;
    float4 v = *(const float4*)(xr + t * 4);
    float s  = v.x + v.y + v.z + v.w;
    float sq = v.x * v.x + v.y * v.y + v.z * v.z + v.w * v.w;
    #pragma unroll
    for (int o = 1; o < 64; o <<= 1) {
        s  += __shfl_xor(s, o);
        sq += __shfl_xor(sq, o);
    }
    __shared__ float ws[8];
    int wv = t >> 6;
    if ((t & 63) == 0) { ws[wv * 2] = s; ws[wv * 2 + 1] = sq; }
    __syncthreads();
    s  = ws[0] + ws[2] + ws[4] + ws[6];
    sq = ws[1] + ws[3] + ws[5] + ws[7];
    float mean = s * (1.0f / D_MODEL);
    float var  = (sq - (float)D_MODEL * mean * mean) * (1.0f / (D_MODEL - 1));
    var = fmaxf(var, 0.0f);
    float inv = 1.0f / (sqrtf(var) + 1e-5f);
    #pragma unroll
    for (int j = 0; j < 4; ++j) {
        int c = t * 4 + j;
        float xv = (&v.x)[j];
        out[(size_t)row * D_MODEL + c] = (bf16)(shift[c] + scale[c] * (xv - mean) * inv);
    }
}

// ---------------- MFMA GEMM:  C[M,N] = A[M,K] * Bw[N,K]^T  ----------------
// EPI 0: split into q/k/v buffers [B,H,S,HD], q scaled by 1/8
// EPI 1: outf = resid + C + bias          (fp32 out)
// EPI 2: ob0  = gelu(C + bias)            (bf16 out, row stride N)
template <int EPI>
__global__ __launch_bounds__(256) void gemm_nt(
    const bf16* __restrict__ A, const bf16* __restrict__ Bw,
    const float* __restrict__ bias, const float* __restrict__ resid,
    float* __restrict__ outf, bf16* __restrict__ ob0,
    bf16* __restrict__ ob1, bf16* __restrict__ ob2,
    int M, int N, int K) {
    __shared__ __align__(16) bf16 As[128 * 32];
    __shared__ __align__(16) bf16 Bs[128 * 32];
    int m0 = blockIdx.y * 128, n0 = blockIdx.x * 128;
    int t = threadIdx.x;
    int lane = t & 63, wave = t >> 6;
    int wm = wave >> 1, wn = wave & 1;
    int quad = lane >> 4, l16 = lane & 15;

    v4f acc[4][4];
    #pragma unroll
    for (int i = 0; i < 4; ++i)
        #pragma unroll
        for (int j = 0; j < 4; ++j)
            acc[i][j] = (v4f){0.f, 0.f, 0.f, 0.f};

    for (int k0 = 0; k0 < K; k0 += 32) {
        __syncthreads();
        #pragma unroll
        for (int ii = 0; ii < 2; ++ii) {
            int idx = t + ii * 256;
            int r = idx >> 2, c = (idx & 3) * 8;
            *(uint4*)(&As[r * 32 + c]) = *(const uint4*)(A  + (size_t)(m0 + r) * K + k0 + c);
            *(uint4*)(&Bs[r * 32 + c]) = *(const uint4*)(Bw + (size_t)(n0 + r) * K + k0 + c);
        }
        __syncthreads();
        v8bf af[4], bfr[4];
        #pragma unroll
        for (int i = 0; i < 4; ++i)
            af[i] = *(const v8bf*)(&As[(wm * 64 + i * 16 + l16) * 32 + quad * 8]);
        #pragma unroll
        for (int j = 0; j < 4; ++j)
            bfr[j] = *(const v8bf*)(&Bs[(wn * 64 + j * 16 + l16) * 32 + quad * 8]);
        #pragma unroll
        for (int i = 0; i < 4; ++i)
            #pragma unroll
            for (int j = 0; j < 4; ++j)
                acc[i][j] = __builtin_amdgcn_mfma_f32_16x16x32_bf16(af[i], bfr[j], acc[i][j], 0, 0, 0);
    }

    #pragma unroll
    for (int i = 0; i < 4; ++i) {
        #pragma unroll
        for (int j = 0; j < 4; ++j) {
            #pragma unroll
            for (int r = 0; r < 4; ++r) {
                int row = m0 + wm * 64 + i * 16 + quad * 4 + r;
                int col = n0 + wn * 64 + j * 16 + l16;
                float v = acc[i][j][r];
                if (EPI == 0) {
                    int which = col >> 10, rr = col & 1023;
                    int h = rr >> 6, d = rr & 63;
                    int b = row >> 11, sI = row & 2047;
                    size_t dst = (((size_t)(b * NH + h)) * SEQ + sI) * HDIM + d;
                    if (which == 0) v *= 0.125f;
                    bf16* buf = (which == 0) ? ob0 : ((which == 1) ? ob1 : ob2);
                    buf[dst] = (bf16)v;
                } else if (EPI == 1) {
                    size_t o = (size_t)row * N + col;
                    outf[o] = resid[o] + v + bias[col];
                } else {
                    float u = v + bias[col];
                    float g = 0.5f * u * (1.0f + tanhf(0.7978845608028654f * (u + 0.044715f * u * u * u)));
                    ob0[(size_t)row * N + col] = (bf16)g;
                }
            }
        }
    }
}

// ---------------- Flash attention (causal), per-wave 16 q-rows ----------------
// q,k,v: [B*H, SEQ, HD] bf16 (q pre-scaled by 1/8). out: [B,S,D] bf16.
__global__ __launch_bounds__(256) void attn_kernel(
    const bf16* __restrict__ qb, const bf16* __restrict__ kb,
    const bf16* __restrict__ vb, bf16* __restrict__ ob) {
    int bh = blockIdx.y;            // 0..B*H-1
    int qbase = blockIdx.x * 64;    // 64 q rows per block
    int t = threadIdx.x;
    int wave = t >> 6, lane = t & 63;
    int quad = lane >> 4, l16 = lane & 15;

    const bf16* Qh = qb + (size_t)bh * SEQ * HDIM;
    const bf16* Kh = kb + (size_t)bh * SEQ * HDIM;
    const bf16* Vh = vb + (size_t)bh * SEQ * HDIM;

    __shared__ __align__(16) bf16 Ks[32 * 64];       // [key][dim]
    __shared__ __align__(16) bf16 Vts[64 * 32];      // [dim][key]
    __shared__ __align__(16) bf16 Ps[4][16 * 32];    // per-wave P

    int qrow = qbase + wave * 16 + l16;
    v8bf qf0 = *(const v8bf*)(Qh + (size_t)qrow * HDIM + quad * 8);
    v8bf qf1 = *(const v8bf*)(Qh + (size_t)qrow * HDIM + 32 + quad * 8);

    v4f o[4];
    #pragma unroll
    for (int dc = 0; dc < 4; ++dc) o[dc] = (v4f){0.f, 0.f, 0.f, 0.f};
    float mrow[4] = {-1e30f, -1e30f, -1e30f, -1e30f};
    float lrow[4] = {0.f, 0.f, 0.f, 0.f};

    int kv_end = qbase + 64;
    for (int kv = 0; kv < kv_end; kv += 32) {
        __syncthreads();
        {
            int r = t >> 3, c8 = (t & 7) * 8;
            *(uint4*)(&Ks[r * 64 + c8]) = *(const uint4*)(Kh + (size_t)(kv + r) * HDIM + c8);
            v8bf vv = *(const v8bf*)(Vh + (size_t)(kv + r) * HDIM + c8);
            #pragma unroll
            for (int j = 0; j < 8; ++j) Vts[(c8 + j) * 32 + r] = vv[j];
        }
        __syncthreads();

        v4f s0 = (v4f){0.f, 0.f, 0.f, 0.f};
        v4f s1 = (v4f){0.f, 0.f, 0.f, 0.f};
        v8bf k0a = *(const v8bf*)(&Ks[l16 * 64 + quad * 8]);
        v8bf k0b = *(const v8bf*)(&Ks[l16 * 64 + 32 + quad * 8]);
        v8bf k1a = *(const v8bf*)(&Ks[(16 + l16) * 64 + quad * 8]);
        v8bf k1b = *(const v8bf*)(&Ks[(16 + l16) * 64 + 32 + quad * 8]);
        s0 = __builtin_amdgcn_mfma_f32_16x16x32_bf16(qf0, k0a, s0, 0, 0, 0);
        s0 = __builtin_amdgcn_mfma_f32_16x16x32_bf16(qf1, k0b, s0, 0, 0, 0);
        s1 = __builtin_amdgcn_mfma_f32_16x16x32_bf16(qf0, k1a, s1, 0, 0, 0);
        s1 = __builtin_amdgcn_mfma_f32_16x16x32_bf16(qf1, k1b, s1, 0, 0, 0);

        int key0 = kv + l16, key1 = kv + 16 + l16;
        #pragma unroll
        for (int r = 0; r < 4; ++r) {
            int qg = qbase + wave * 16 + quad * 4 + r;
            float v0 = (key0 <= qg) ? s0[r] : -1e30f;
            float v1 = (key1 <= qg) ? s1[r] : -1e30f;
            float mx = fmaxf(v0, v1);
            #pragma unroll
            for (int off = 1; off < 16; off <<= 1) mx = fmaxf(mx, __shfl_xor(mx, off));
            float mnew = fmaxf(mrow[r], mx);
            float alpha = __expf(mrow[r] - mnew);
            float p0 = __expf(v0 - mnew);
            float p1 = __expf(v1 - mnew);
            float ps = p0 + p1;
            #pragma unroll
            for (int off = 1; off < 16; off <<= 1) ps += __shfl_xor(ps, off);
            lrow[r] = lrow[r] * alpha + ps;
            mrow[r] = mnew;
            #pragma unroll
            for (int dc = 0; dc < 4; ++dc) o[dc][r] *= alpha;
            Ps[wave][(quad * 4 + r) * 32 + l16]      = (bf16)p0;
            Ps[wave][(quad * 4 + r) * 32 + 16 + l16] = (bf16)p1;
        }
        __syncthreads();

        v8bf pf = *(const v8bf*)(&Ps[wave][l16 * 32 + quad * 8]);
        #pragma unroll
        for (int dc = 0; dc < 4; ++dc) {
            v8bf vf = *(const v8bf*)(&Vts[(dc * 16 + l16) * 32 + quad * 8]);
            o[dc] = __builtin_amdgcn_mfma_f32_16x16x32_bf16(pf, vf, o[dc], 0, 0, 0);
        }
    }

    int b = bh >> 4, h = bh & 15;
    #pragma unroll
    for (int dc = 0; dc < 4; ++dc) {
        #pragma unroll
        for (int r = 0; r < 4; ++r) {
            int sidx = qbase + wave * 16 + quad * 4 + r;
            int d = dc * 16 + l16;
            float val = o[dc][r] / lrow[r];
            ob[((size_t)(b * SEQ + sidx)) * D_MODEL + h * HDIM + d] = (bf16)val;
        }
    }
}

// ---------------- launch ----------------
extern "C" void kernel_launch(void* const* d_in, const int* in_sizes, int n_in,
                              void* d_out, int out_size, void* d_ws, size_t ws_size,
                              hipStream_t stream) {
    const float* x      = (const float*)d_in[0];
    const float* scale1 = (const float*)d_in[1];
    const float* shift1 = (const float*)d_in[2];
    const float* Wqkv   = (const float*)d_in[3];
    const float* Wo_w   = (const float*)d_in[4];
    const float* Wo_b   = (const float*)d_in[5];
    const float* scale2 = (const float*)d_in[6];
    const float* shift2 = (const float*)d_in[7];
    const float* W1     = (const float*)d_in[8];
    const float* b1     = (const float*)d_in[9];
    const float* W2     = (const float*)d_in[10];
    const float* b2     = (const float*)d_in[11];
    float* out = (float*)d_out;

    char* ws = (char*)d_ws;
    size_t off = 0;
    auto alloc = [&](size_t bytes) -> char* {
        char* p = ws + off;
        off += (bytes + 255) & ~(size_t)255;
        return p;
    };
    bf16* Wqkv_b = (bf16*)alloc((size_t)3 * D_MODEL * D_MODEL * 2);
    bf16* Wo_bf  = (bf16*)alloc((size_t)D_MODEL * D_MODEL * 2);
    bf16* W1_b   = (bf16*)alloc((size_t)FF_DIM * D_MODEL * 2);
    bf16* W2_b   = (bf16*)alloc((size_t)D_MODEL * FF_DIM * 2);
    bf16* bufA   = (bf16*)alloc((size_t)NTOK * D_MODEL * 2);   // h1, then attn out
    bf16* qb     = (bf16*)alloc((size_t)NTOK * D_MODEL * 2);   // q, then h2
    bf16* kb     = (bf16*)alloc((size_t)NTOK * D_MODEL * 2);
    bf16* vb     = (bf16*)alloc((size_t)NTOK * D_MODEL * 2);
    float* x1    = (float*)alloc((size_t)NTOK * D_MODEL * 4);
    bf16* mbuf   = (bf16*)alloc((size_t)NTOK * FF_DIM * 2);
    (void)ws_size; (void)n_in; (void)in_sizes; (void)out_size;

    f32_to_bf16_kernel<<<3 * D_MODEL * D_MODEL / 1024, 256, 0, stream>>>(Wqkv, Wqkv_b, 3 * D_MODEL * D_MODEL);
    f32_to_bf16_kernel<<<D_MODEL * D_MODEL / 1024, 256, 0, stream>>>(Wo_w, Wo_bf, D_MODEL * D_MODEL);
    f32_to_bf16_kernel<<<FF_DIM * D_MODEL / 1024, 256, 0, stream>>>(W1, W1_b, FF_DIM * D_MODEL);
    f32_to_bf16_kernel<<<FF_DIM * D_MODEL / 1024, 256, 0, stream>>>(W2, W2_b, D_MODEL * FF_DIM);

    layernorm_kernel<<<NTOK, 256, 0, stream>>>(x, scale1, shift1, bufA);

    gemm_nt<0><<<dim3(3 * D_MODEL / 128, NTOK / 128), 256, 0, stream>>>(
        bufA, Wqkv_b, nullptr, nullptr, nullptr, qb, kb, vb, NTOK, 3 * D_MODEL, D_MODEL);

    attn_kernel<<<dim3(SEQ / 64, 2 * NH), 256, 0, stream>>>(qb, kb, vb, bufA);

    gemm_nt<1><<<dim3(D_MODEL / 128, NTOK / 128), 256, 0, stream>>>(
        bufA, Wo_bf, Wo_b, x, x1, nullptr, nullptr, nullptr, NTOK, D_MODEL, D_MODEL);

    layernorm_kernel<<<NTOK, 256, 0, stream>>>(x1, scale2, shift2, qb);

    gemm_nt<2><<<dim3(FF_DIM / 128, NTOK / 128), 256, 0, stream>>>(
        qb, W1_b, b1, nullptr, nullptr, mbuf, nullptr, nullptr, NTOK, FF_DIM, D_MODEL);

    gemm_nt<1><<<dim3(D_MODEL / 128, NTOK / 128), 256, 0, stream>>>(
        mbuf, W2_b, b2, x1, out, nullptr, nullptr, nullptr, NTOK, D_MODEL, FF_DIM);
}